// Round 1
// baseline (99.629 us; speedup 1.0000x reference)
//
#include <hip/hip_runtime.h>

// Bernstein->monomial basis change, degree 5, with input remap t=(x+1)/2 folded in:
// B_i((x+1)/2) = C(5,i) * 2^-5 * (1+x)^i (1-x)^(5-i) = sum_d Mb[i][d] * x^d
// Entries are integer/32 (exact in fp32).
__device__ __constant__ float Mb[6][6] = {
    { 0.03125f, -0.15625f,  0.3125f, -0.3125f,  0.15625f, -0.03125f},
    { 0.15625f, -0.46875f,  0.3125f,  0.3125f, -0.46875f,  0.15625f},
    { 0.3125f,  -0.3125f,  -0.625f,   0.625f,   0.3125f,  -0.3125f },
    { 0.3125f,   0.3125f,  -0.625f,  -0.625f,   0.3125f,   0.3125f },
    { 0.15625f,  0.46875f,  0.3125f, -0.3125f, -0.46875f, -0.15625f},
    { 0.03125f,  0.15625f,  0.3125f,  0.3125f,  0.15625f,  0.03125f},
};

// One block. Converts p[3][6][6][6] (Bernstein) -> A[3][6][6][6] (monomial coeffs
// in raw x,y,z in [-1,1]), with output transform q' = 2q - 1 folded in.
// Staged separable transforms: k axis, then j, then i. 648 elements per stage.
__global__ void ffd_coeff(const float* __restrict__ p, float* __restrict__ A)
{
    __shared__ float b0[648];
    __shared__ float b1[648];
    const int t = threadIdx.x;

    for (int m = t; m < 648; m += 256) b0[m] = p[m];
    __syncthreads();

    // stage 1: transform k -> dk  (b0 -> b1)
    for (int m = t; m < 648; m += 256) {
        const int dk = m % 6;
        const int base = (m / 6) * 6;
        float s = 0.f;
        #pragma unroll
        for (int k = 0; k < 6; ++k) s = fmaf(b0[base + k], Mb[k][dk], s);
        b1[m] = s;
    }
    __syncthreads();

    // stage 2: transform j -> dj  (b1 -> b0)
    for (int m = t; m < 648; m += 256) {
        const int dk = m % 6;
        const int dj = (m / 6) % 6;
        const int ci = m / 36;               // ci = c*6 + i
        float s = 0.f;
        #pragma unroll
        for (int j = 0; j < 6; ++j) s = fmaf(b1[(ci * 6 + j) * 6 + dk], Mb[j][dj], s);
        b0[m] = s;
    }
    __syncthreads();

    // stage 3: transform i -> di, apply 2*q - 1  (b0 -> A in global)
    for (int m = t; m < 648; m += 256) {
        const int dk = m % 6;
        const int dj = (m / 6) % 6;
        const int di = (m / 36) % 6;
        const int c  = m / 216;
        float s = 0.f;
        #pragma unroll
        for (int i = 0; i < 6; ++i) s = fmaf(b0[((c * 6 + i) * 6 + dj) * 6 + dk], Mb[i][di], s);
        s *= 2.0f;
        if (di == 0 && dj == 0 && dk == 0) s -= 1.0f;
        A[m] = s;
    }
}

// Main kernel: 4 vertices per thread. Nested Horner evaluation
//   q_c(x,y,z) = H_i( H_j( H_k(A[c][i][j][k]; z); y ); x )
// 645 FMAs/vertex. All A accesses are wave-uniform -> scalar (s_load) path.
__global__ __launch_bounds__(256) void ffd_eval(const float* __restrict__ verts,
                                                const float* __restrict__ A,
                                                float* __restrict__ out, int N)
{
    const int t = blockIdx.x * blockDim.x + threadIdx.x;
    const long long v0 = (long long)t * 4;
    if (v0 >= N) return;

    float x[4], y[4], z[4];
    const bool full = (v0 + 4 <= N);
    if (full) {
        const float4* vp = (const float4*)(verts + v0 * 3);  // 48B offset -> 16B aligned
        const float4 f0 = vp[0], f1 = vp[1], f2 = vp[2];
        x[0] = f0.x; y[0] = f0.y; z[0] = f0.z;
        x[1] = f0.w; y[1] = f1.x; z[1] = f1.y;
        x[2] = f1.z; y[2] = f1.w; z[2] = f2.x;
        x[3] = f2.y; y[3] = f2.z; z[3] = f2.w;
    } else {
        for (int v = 0; v < 4; ++v) {
            long long n = v0 + v; if (n >= N) n = N - 1;
            x[v] = verts[n * 3 + 0]; y[v] = verts[n * 3 + 1]; z[v] = verts[n * 3 + 2];
        }
    }

    float res[12];
    #pragma unroll
    for (int c = 0; c < 3; ++c) {
        float q[4];
        #pragma unroll
        for (int ii = 0; ii < 6; ++ii) {
            const int i = 5 - ii;
            float tj[4];
            #pragma unroll
            for (int jj = 0; jj < 6; ++jj) {
                const int j = 5 - jj;
                const float* Ak = A + ((c * 6 + i) * 6 + j) * 6;
                const float a0 = Ak[0], a1 = Ak[1], a2 = Ak[2],
                            a3 = Ak[3], a4 = Ak[4], a5 = Ak[5];
                #pragma unroll
                for (int v = 0; v < 4; ++v) {
                    float s = fmaf(a5, z[v], a4);
                    s = fmaf(s, z[v], a3);
                    s = fmaf(s, z[v], a2);
                    s = fmaf(s, z[v], a1);
                    s = fmaf(s, z[v], a0);
                    tj[v] = (jj == 0) ? s : fmaf(tj[v], y[v], s);
                }
            }
            #pragma unroll
            for (int v = 0; v < 4; ++v)
                q[v] = (ii == 0) ? tj[v] : fmaf(q[v], x[v], tj[v]);
        }
        #pragma unroll
        for (int v = 0; v < 4; ++v) res[v * 3 + c] = q[v];
    }

    if (full) {
        float4* op = (float4*)(out + v0 * 3);
        op[0] = make_float4(res[0], res[1], res[2],  res[3]);
        op[1] = make_float4(res[4], res[5], res[6],  res[7]);
        op[2] = make_float4(res[8], res[9], res[10], res[11]);
    } else {
        for (int v = 0; v < 4; ++v) {
            const long long n = v0 + v;
            if (n < N) {
                out[n * 3 + 0] = res[v * 3 + 0];
                out[n * 3 + 1] = res[v * 3 + 1];
                out[n * 3 + 2] = res[v * 3 + 2];
            }
        }
    }
}

extern "C" void kernel_launch(void* const* d_in, const int* in_sizes, int n_in,
                              void* d_out, int out_size, void* d_ws, size_t ws_size,
                              hipStream_t stream)
{
    const float* verts = (const float*)d_in[0];   // [N,3] fp32
    const float* p     = (const float*)d_in[1];   // [3,6,6,6] fp32
    float* out = (float*)d_out;                   // [1,N,3] fp32
    float* A   = (float*)d_ws;                    // 648 floats scratch
    const int N = in_sizes[0] / 3;

    ffd_coeff<<<1, 256, 0, stream>>>(p, A);

    const int nthreads = (N + 3) / 4;
    const int blocks = (nthreads + 255) / 256;
    ffd_eval<<<blocks, 256, 0, stream>>>(verts, A, out, N);
}

// Round 2
// 80.171 us; speedup vs baseline: 1.2427x; 1.2427x over previous
//
#include <hip/hip_runtime.h>

// Bernstein->monomial basis change, degree 5, with input remap t=(x+1)/2 folded in:
// B_i((x+1)/2) = sum_d Mb[i][d] * x^d   (entries exact in fp32: integer/32)
__device__ __constant__ float Mb[6][6] = {
    { 0.03125f, -0.15625f,  0.3125f, -0.3125f,  0.15625f, -0.03125f},
    { 0.15625f, -0.46875f,  0.3125f,  0.3125f, -0.46875f,  0.15625f},
    { 0.3125f,  -0.3125f,  -0.625f,   0.625f,   0.3125f,  -0.3125f },
    { 0.3125f,   0.3125f,  -0.625f,  -0.625f,   0.3125f,   0.3125f },
    { 0.15625f,  0.46875f,  0.3125f, -0.3125f, -0.46875f, -0.15625f},
    { 0.03125f,  0.15625f,  0.3125f,  0.3125f,  0.15625f,  0.03125f},
};

// Fused kernel. Phase 1: every block converts p[3][6][6][6] (Bernstein) ->
// monomial coeffs A in its own LDS (redundant across blocks; ~12k FMAs, free).
// Phase 2: 4 vertices/thread, nested Horner. Coefficients are pulled from LDS
// in 36-float chunks (9x ds_read_b128, uniform addr -> broadcast) inside a
// DYNAMIC (c,i) loop so only 36 coeffs are live at a time (bounded VGPRs,
// no giant unrolled global-load body — that was the 100us latency bug in R1).
__global__ __launch_bounds__(256) void ffd_fused(const float* __restrict__ verts,
                                                 const float* __restrict__ p,
                                                 float* __restrict__ out, int N)
{
    __shared__ __align__(16) float b0[648];
    __shared__ __align__(16) float b1[648];
    const int t = threadIdx.x;

    // ---- Phase 1: separable basis change in LDS ----
    for (int m = t; m < 648; m += 256) b0[m] = p[m];
    __syncthreads();

    // k -> dk  (b0 -> b1)
    for (int m = t; m < 648; m += 256) {
        const int dk = m % 6;
        const int base = (m / 6) * 6;
        float s = 0.f;
        #pragma unroll
        for (int k = 0; k < 6; ++k) s = fmaf(b0[base + k], Mb[k][dk], s);
        b1[m] = s;
    }
    __syncthreads();

    // j -> dj  (b1 -> b0)
    for (int m = t; m < 648; m += 256) {
        const int dk = m % 6;
        const int dj = (m / 6) % 6;
        const int ci = m / 36;               // ci = c*6 + i
        float s = 0.f;
        #pragma unroll
        for (int j = 0; j < 6; ++j) s = fmaf(b1[(ci * 6 + j) * 6 + dk], Mb[j][dj], s);
        b0[m] = s;
    }
    __syncthreads();

    // i -> di, fold in q' = 2q - 1  (b0 -> b1). b1 = final coeffs A[c][i][j][k].
    for (int m = t; m < 648; m += 256) {
        const int dk = m % 6;
        const int dj = (m / 6) % 6;
        const int di = (m / 36) % 6;
        const int c  = m / 216;
        float s = 0.f;
        #pragma unroll
        for (int i = 0; i < 6; ++i) s = fmaf(b0[((c * 6 + i) * 6 + dj) * 6 + dk], Mb[i][di], s);
        s *= 2.0f;
        if (di == 0 && dj == 0 && dk == 0) s -= 1.0f;
        b1[m] = s;
    }
    __syncthreads();

    // ---- Phase 2: evaluation, 4 vertices per thread ----
    const long long v0 = ((long long)blockIdx.x * 256 + t) * 4;
    if (v0 >= N) return;

    float x[4], y[4], z[4];
    const bool full = (v0 + 4 <= N);
    if (full) {
        const float4* vp = (const float4*)(verts + v0 * 3);  // 48B stride -> 16B aligned
        const float4 f0 = vp[0], f1 = vp[1], f2 = vp[2];
        x[0] = f0.x; y[0] = f0.y; z[0] = f0.z;
        x[1] = f0.w; y[1] = f1.x; z[1] = f1.y;
        x[2] = f1.z; y[2] = f1.w; z[2] = f2.x;
        x[3] = f2.y; y[3] = f2.z; z[3] = f2.w;
    } else {
        for (int v = 0; v < 4; ++v) {
            long long n = v0 + v; if (n >= N) n = N - 1;
            x[v] = verts[n * 3 + 0]; y[v] = verts[n * 3 + 1]; z[v] = verts[n * 3 + 2];
        }
    }

    float res[12];
    #pragma unroll 1
    for (int c = 0; c < 3; ++c) {
        float q[4];
        #pragma unroll 1
        for (int ii = 0; ii < 6; ++ii) {
            const int i = 5 - ii;
            // Pull this (c,i)-block's 36 coefficients from LDS (uniform addr
            // -> broadcast; 9x ds_read_b128, 16B-aligned since 36 floats=144B).
            const float4* blk = (const float4*)(b1 + (c * 6 + i) * 36);
            float a[36];
            #pragma unroll
            for (int r = 0; r < 9; ++r) {
                const float4 f = blk[r];
                a[r * 4 + 0] = f.x; a[r * 4 + 1] = f.y;
                a[r * 4 + 2] = f.z; a[r * 4 + 3] = f.w;
            }
            float tj[4];
            #pragma unroll
            for (int jj = 0; jj < 6; ++jj) {
                const int j = 5 - jj;
                const float* Ak = a + j * 6;
                #pragma unroll
                for (int v = 0; v < 4; ++v) {
                    float s = fmaf(Ak[5], z[v], Ak[4]);
                    s = fmaf(s, z[v], Ak[3]);
                    s = fmaf(s, z[v], Ak[2]);
                    s = fmaf(s, z[v], Ak[1]);
                    s = fmaf(s, z[v], Ak[0]);
                    tj[v] = (jj == 0) ? s : fmaf(tj[v], y[v], s);
                }
            }
            #pragma unroll
            for (int v = 0; v < 4; ++v)
                q[v] = (ii == 0) ? tj[v] : fmaf(q[v], x[v], tj[v]);
        }
        #pragma unroll
        for (int v = 0; v < 4; ++v) res[v * 3 + c] = q[v];
    }

    if (full) {
        float4* op = (float4*)(out + v0 * 3);
        op[0] = make_float4(res[0], res[1], res[2],  res[3]);
        op[1] = make_float4(res[4], res[5], res[6],  res[7]);
        op[2] = make_float4(res[8], res[9], res[10], res[11]);
    } else {
        for (int v = 0; v < 4; ++v) {
            const long long n = v0 + v;
            if (n < N) {
                out[n * 3 + 0] = res[v * 3 + 0];
                out[n * 3 + 1] = res[v * 3 + 1];
                out[n * 3 + 2] = res[v * 3 + 2];
            }
        }
    }
}

extern "C" void kernel_launch(void* const* d_in, const int* in_sizes, int n_in,
                              void* d_out, int out_size, void* d_ws, size_t ws_size,
                              hipStream_t stream)
{
    const float* verts = (const float*)d_in[0];   // [N,3] fp32
    const float* p     = (const float*)d_in[1];   // [3,6,6,6] fp32
    float* out = (float*)d_out;                   // [1,N,3] fp32
    const int N = in_sizes[0] / 3;

    const int nthreads = (N + 3) / 4;
    const int blocks = (nthreads + 255) / 256;
    ffd_fused<<<blocks, 256, 0, stream>>>(verts, p, out, N);
}